// Round 11
// baseline (158.202 us; speedup 1.0000x reference)
//
#include <hip/hip_runtime.h>

#define NB_B  2
#define NB_Q  10000
#define NB_D  256
#define NB_NH 8
#define NB_NL 4
#define NB_NP 4
#define NB_HD 32
#define NB_S  21760   // 128*128 + 64*64 + 32*32 + 16*16
#define MQ    20000   // B*Q
#define MQB   313     // ceil(20000/64)
#define NVB   1360    // (B*S/64)*2  vproj blocks
#define NCB   939     // MQB*3       coords blocks

#define AROW  36      // A LDS row stride in halfs (72B) -> conflict-free

typedef _Float16 half8 __attribute__((ext_vector_type(8)));
typedef float f32x4 __attribute__((ext_vector_type(4)));

// ---------------------------------------------------------------------------
// Prep: transpose + fp16-convert weights to Wt[n][k] (k-major, 256 k each).
// ---------------------------------------------------------------------------
__global__ __launch_bounds__(256) void k_prepw(const float* __restrict__ Wv,
                                               const float* __restrict__ Ws,
                                               const float* __restrict__ Wa,
                                               const float* __restrict__ Wo,
                                               _Float16* __restrict__ Wvt,
                                               _Float16* __restrict__ Wsat,
                                               _Float16* __restrict__ Wot)
{
    const int k = threadIdx.x;
    const int nc = blockIdx.x;
    if (nc < 256) {
        Wvt[nc * 256 + k] = (_Float16)Wv[k * 256 + nc];
    } else if (nc < 640) {
        const int n = nc - 256;
        const float v = (n < 256) ? Ws[k * 256 + n] : Wa[k * 128 + (n - 256)];
        Wsat[n * 256 + k] = (_Float16)v;
    } else {
        const int n = nc - 640;
        Wot[n * 256 + k] = (_Float16)Wo[k * 256 + n];
    }
}

// ---------------------------------------------------------------------------
// k_front: co-launched vproj [0,NVB) + coords [NVB,NVB+NCB).
// BM=64, BN=128, BK=32, ROW-SPLIT waves: wave w owns rows [w*16,w*16+16).
// A staged in wave-PRIVATE LDS (no barriers in K-loop!); B fragments read
// directly from L2-resident transposed weights with register prefetch-1.
// A LDS [16][36] halfs: writes/reads <=2-way bank aliasing (free).
// ---------------------------------------------------------------------------
__global__ __launch_bounds__(256) void k_front(const float* __restrict__ value,
                                               const float* __restrict__ query,
                                               const _Float16* __restrict__ Wvt,
                                               const _Float16* __restrict__ Wsat,
                                               const float* __restrict__ refp,
                                               const float* __restrict__ bv,
                                               const float* __restrict__ bs,
                                               const float* __restrict__ ba,
                                               _Float16* __restrict__ vt,
                                               float* __restrict__ sx,
                                               float* __restrict__ sy,
                                               float* __restrict__ sw)
{
    __shared__ _Float16 Ah[2][4][16 * AROW];   // [buf][wave][row][36]  9216 B
    __shared__ float rp[64][8];                // coords only, 2 KB

    const int t = threadIdx.x;
    const int lane = t & 63, w = t >> 6;
    const int bid = blockIdx.x;
    const bool isv = (bid < NVB);

    int row0, n0;
    const float* Asrc;
    const _Float16* Bsrc;
    if (isv) {
        n0 = (bid & 1) * 128;
        row0 = (bid >> 1) * 64;
        Asrc = value;
        Bsrc = Wvt;
    } else {
        const int cid = bid - NVB;
        n0 = (cid % 3) * 128;
        row0 = (cid / 3) * 64;
        Asrc = query;
        Bsrc = Wsat;
        const int i0 = row0 * 8 + t;
        rp[t >> 3][t & 7] = refp[min(i0, MQ * 8 - 1)];
        const int i1 = i0 + 256;
        rp[32 + (t >> 3)][t & 7] = refp[min(i1, MQ * 8 - 1)];
    }

    // ---- A staging (wave-private): lane -> rows {srow, srow+8}, float4-col scol
    const int srow = lane >> 3, scol = lane & 7;
    int r0i = row0 + w * 16 + srow, r1i = r0i + 8;
    if (!isv) { r0i = min(r0i, MQ - 1); r1i = min(r1i, MQ - 1); }
    const float* gA0 = Asrc + (size_t)r0i * 256 + scol * 4;
    const float* gA1 = Asrc + (size_t)r1i * 256 + scol * 4;
    _Float16* myA0 = &Ah[0][w][0];
    _Float16* myA1 = &Ah[1][w][0];

    // ---- B fragment base: lane -> n = n0 + fc*16 + rowb, k-oct kq
    const int rowb = lane & 15, kq = lane >> 4;
    const _Float16* gB = Bsrc + (size_t)(n0 + rowb) * 256 + kq * 8;

    float4 a0, a1;
#define LOADA(kt) { a0 = *reinterpret_cast<const float4*>(gA0 + (kt) * 32); \
                    a1 = *reinterpret_cast<const float4*>(gA1 + (kt) * 32); }
#define WRITEA(dst) { \
        union { _Float16 h[4]; uint2 u; } p0, p1; \
        p0.h[0] = (_Float16)a0.x; p0.h[1] = (_Float16)a0.y; \
        p0.h[2] = (_Float16)a0.z; p0.h[3] = (_Float16)a0.w; \
        p1.h[0] = (_Float16)a1.x; p1.h[1] = (_Float16)a1.y; \
        p1.h[2] = (_Float16)a1.z; p1.h[3] = (_Float16)a1.w; \
        *reinterpret_cast<uint2*>(&(dst)[srow * AROW + scol * 4]) = p0.u; \
        *reinterpret_cast<uint2*>(&(dst)[(srow + 8) * AROW + scol * 4]) = p1.u; }

    f32x4 acc[8];
#pragma unroll
    for (int fc = 0; fc < 8; ++fc) acc[fc] = (f32x4){0.f, 0.f, 0.f, 0.f};

    // prologue: tile0 -> LDS buf0; tile1 -> regs; B frags for kt=0 -> regs
    LOADA(0); WRITEA(myA0); LOADA(1);
    half8 bfc[8], bfn[8];
#pragma unroll
    for (int fc = 0; fc < 8; ++fc)
        bfc[fc] = *reinterpret_cast<const half8*>(gB + fc * 4096);

#pragma unroll
    for (int kt = 0; kt < 8; ++kt) {
        // prefetch next B fragments
        if (kt < 7) {
#pragma unroll
            for (int fc = 0; fc < 8; ++fc)
                bfn[fc] = *reinterpret_cast<const half8*>(gB + fc * 4096 + (kt + 1) * 32);
        }
        // A fragment (own wave's LDS; lgkmcnt ordering only)
        _Float16* cur = (kt & 1) ? myA1 : myA0;
        const half8 af = *reinterpret_cast<const half8*>(&cur[rowb * AROW + kq * 8]);
        // stage tile kt+1 (regs->LDS other buf), load tile kt+2
        _Float16* nxt = (kt & 1) ? myA0 : myA1;
        if (kt < 7) WRITEA(nxt);
        if (kt < 6) LOADA(kt + 2);
        // 8 MFMAs: rows w*16.., cols fc*16..
#pragma unroll
        for (int fc = 0; fc < 8; ++fc)
            acc[fc] = __builtin_amdgcn_mfma_f32_16x16x32_f16(af, bfc[fc], acc[fc], 0, 0, 0);
#pragma unroll
        for (int fc = 0; fc < 8; ++fc) bfc[fc] = bfn[fc];
    }
#undef LOADA
#undef WRITEA

    __syncthreads();   // only barrier: rp visibility for epilogue

    // ---- epilogues: wave w owns rows row0+w*16.., cols n0+fc*16+rowb ----
    const int mrow = w * 16 + (lane >> 4) * 4;   // +j
    if (isv) {
        const int b = (row0 >= NB_S) ? 1 : 0;
        const int sb = row0 - b * NB_S;
#pragma unroll
        for (int fc = 0; fc < 8; ++fc) {
            const int n = n0 + fc * 16 + rowb;
            const int h = n >> 5, hd = n & 31;
            const float bvn = bv[n];
            const f32x4 c = acc[fc];
#pragma unroll
            for (int j = 0; j < 4; ++j) {
                const int m = mrow + j;
                vt[((size_t)((b * NB_NH + h) * NB_S + (sb + m)) << 5) + hd] = (_Float16)(c[j] + bvn);
            }
        }
    } else if (n0 < 256) {
#pragma unroll
        for (int fc = 0; fc < 8; ++fc) {
            const int n = n0 + fc * 16 + rowb;
            const int si = n >> 1, xy = n & 1;
            const int l = (n >> 3) & 3;
            const float dim = (float)(128 >> l);
            const float bsv = bs[n];
            float* dst = xy ? sy : sx;
            const f32x4 c = acc[fc];
#pragma unroll
            for (int j = 0; j < 4; ++j) {
                const int m = mrow + j;
                if (row0 + m < MQ) {
                    const float coord = rp[m][l * 2 + xy] * dim + (c[j] + bsv) - 0.5f;
                    dst[(size_t)(row0 + m) * 128 + si] = coord;
                }
            }
        }
    } else {
#pragma unroll
        for (int fc = 0; fc < 8; ++fc) {
            const int col = fc * 16 + rowb;
            const float bav = ba[col];
            const f32x4 c = acc[fc];
#pragma unroll
            for (int j = 0; j < 4; ++j) {
                const int m = mrow + j;
                float v = c[j] + bav;
                float vm = v;
                vm = fmaxf(vm, __shfl_xor(vm, 1));
                vm = fmaxf(vm, __shfl_xor(vm, 2));
                vm = fmaxf(vm, __shfl_xor(vm, 4));
                vm = fmaxf(vm, __shfl_xor(vm, 8));
                const float e = expf(v - vm);
                float s = e;
                s += __shfl_xor(s, 1);
                s += __shfl_xor(s, 2);
                s += __shfl_xor(s, 4);
                s += __shfl_xor(s, 8);
                if (row0 + m < MQ)
                    sw[(size_t)(row0 + m) * 128 + col] = e / s;
            }
        }
    }
}

// ---------------------------------------------------------------------------
// gather: block = (16 queries, 1 head); head = blockIdx.x & 7 (XCD locality).
// ---------------------------------------------------------------------------
__global__ __launch_bounds__(256) void k_gather(const _Float16* __restrict__ vt,
                                                const float* __restrict__ sx,
                                                const float* __restrict__ sy,
                                                const float* __restrict__ sw,
                                                _Float16* __restrict__ tmp)
{
    __shared__ int   offs[16][16][4];
    __shared__ float wts[16][16][4];
    const int t = threadIdx.x;
    const int gid = blockIdx.x;
    const int h = gid & 7;
    const int row0 = (gid >> 3) * 16;
    const int b = (row0 >= NB_Q) ? 1 : 0;

    {
        const int r = t >> 4, s = t & 15;
        const size_t ci = (size_t)(row0 + r) * 128 + h * 16 + s;
        const float x = sx[ci], y = sy[ci], w = sw[ci];
        const int l = s >> 2;
        const int dim = 128 >> l;
        const int startL = (l == 0) ? 0 : (l == 1) ? 16384 : (l == 2) ? 20480 : 21504;
        const float x0f = floorf(x), y0f = floorf(y);
        const float lx = x - x0f, ly = y - y0f;
        const int ix = (int)x0f, iy = (int)y0f;
        const int ix0 = min(max(ix, 0), dim - 1), ix1 = min(max(ix + 1, 0), dim - 1);
        const int iy0 = min(max(iy, 0), dim - 1), iy1 = min(max(iy + 1, 0), dim - 1);
        const float vx0 = (ix >= 0 && ix < dim) ? 1.f : 0.f;
        const float vx1 = (ix + 1 >= 0 && ix + 1 < dim) ? 1.f : 0.f;
        const float vy0 = (iy >= 0 && iy < dim) ? 1.f : 0.f;
        const float vy1 = (iy + 1 >= 0 && iy + 1 < dim) ? 1.f : 0.f;
        offs[r][s][0] = (startL + iy0 * dim + ix0) * (NB_HD * 2);
        offs[r][s][1] = (startL + iy0 * dim + ix1) * (NB_HD * 2);
        offs[r][s][2] = (startL + iy1 * dim + ix0) * (NB_HD * 2);
        offs[r][s][3] = (startL + iy1 * dim + ix1) * (NB_HD * 2);
        wts[r][s][0] = w * (1.f - lx) * (1.f - ly) * vx0 * vy0;
        wts[r][s][1] = w * lx * (1.f - ly) * vx1 * vy0;
        wts[r][s][2] = w * (1.f - lx) * ly * vx0 * vy1;
        wts[r][s][3] = w * lx * ly * vx1 * vy1;
    }
    __syncthreads();

    const int r = t >> 4, hd2 = t & 15;
    const char* slab = reinterpret_cast<const char*>(vt)
                     + (size_t)(b * NB_NH + h) * NB_S * (NB_HD * 2);
    const int byo = hd2 * 4;
    float ax = 0.f, ay = 0.f;
#pragma unroll
    for (int s = 0; s < 16; ++s) {
        const int4   o = *reinterpret_cast<const int4*>(&offs[r][s][0]);
        const float4 w = *reinterpret_cast<const float4*>(&wts[r][s][0]);
        union { unsigned u; _Float16 h[2]; } c0, c1, c2, c3;
        c0.u = *reinterpret_cast<const unsigned*>(slab + (o.x + byo));
        c1.u = *reinterpret_cast<const unsigned*>(slab + (o.y + byo));
        c2.u = *reinterpret_cast<const unsigned*>(slab + (o.z + byo));
        c3.u = *reinterpret_cast<const unsigned*>(slab + (o.w + byo));
        ax = fmaf(w.x, (float)c0.h[0], ax); ay = fmaf(w.x, (float)c0.h[1], ay);
        ax = fmaf(w.y, (float)c1.h[0], ax); ay = fmaf(w.y, (float)c1.h[1], ay);
        ax = fmaf(w.z, (float)c2.h[0], ax); ay = fmaf(w.z, (float)c2.h[1], ay);
        ax = fmaf(w.w, (float)c3.h[0], ax); ay = fmaf(w.w, (float)c3.h[1], ay);
    }
    union { unsigned u; _Float16 h[2]; } p;
    p.h[0] = (_Float16)ax; p.h[1] = (_Float16)ay;
    *reinterpret_cast<unsigned*>(tmp + (size_t)(row0 + r) * 256 + h * 32 + hd2 * 2) = p.u;
}

// ---------------------------------------------------------------------------
// oproj: out = tmp @ Wo + bo. Row-split waves, wave-private A (fp16, uint4
// staging, no barriers), B direct from global.
// ---------------------------------------------------------------------------
__global__ __launch_bounds__(256) void k_oproj_mm(const _Float16* __restrict__ tmp,
                                                  const _Float16* __restrict__ Wot,
                                                  const float* __restrict__ bo,
                                                  float* __restrict__ out)
{
    __shared__ _Float16 Ah[2][4][16 * AROW];
    const int t = threadIdx.x;
    const int lane = t & 63, w = t >> 6;
    const int bid = blockIdx.x;
    const int n0 = (bid & 1) * 128;
    const int row0 = (bid >> 1) * 64;

    // A staging: lane -> row srow (0..15), k-oct soct (0..3)
    const int srow = lane >> 2, soct = lane & 3;
    const _Float16* gA = tmp + (size_t)min(row0 + w * 16 + srow, MQ - 1) * 256 + soct * 8;
    _Float16* myA0 = &Ah[0][w][0];
    _Float16* myA1 = &Ah[1][w][0];

    const int rowb = lane & 15, kq = lane >> 4;
    const _Float16* gB = Wot + (size_t)(n0 + rowb) * 256 + kq * 8;

    uint4 a0;
#define LOADA(kt) { a0 = *reinterpret_cast<const uint4*>(gA + (kt) * 32); }
#define WRITEA(dst) { *reinterpret_cast<uint4*>(&(dst)[srow * AROW + soct * 8]) = a0; }

    f32x4 acc[8];
#pragma unroll
    for (int fc = 0; fc < 8; ++fc) acc[fc] = (f32x4){0.f, 0.f, 0.f, 0.f};

    LOADA(0); WRITEA(myA0); LOADA(1);
    half8 bfc[8], bfn[8];
#pragma unroll
    for (int fc = 0; fc < 8; ++fc)
        bfc[fc] = *reinterpret_cast<const half8*>(gB + fc * 4096);

#pragma unroll
    for (int kt = 0; kt < 8; ++kt) {
        if (kt < 7) {
#pragma unroll
            for (int fc = 0; fc < 8; ++fc)
                bfn[fc] = *reinterpret_cast<const half8*>(gB + fc * 4096 + (kt + 1) * 32);
        }
        _Float16* cur = (kt & 1) ? myA1 : myA0;
        const half8 af = *reinterpret_cast<const half8*>(&cur[rowb * AROW + kq * 8]);
        _Float16* nxt = (kt & 1) ? myA0 : myA1;
        if (kt < 7) WRITEA(nxt);
        if (kt < 6) LOADA(kt + 2);
#pragma unroll
        for (int fc = 0; fc < 8; ++fc)
            acc[fc] = __builtin_amdgcn_mfma_f32_16x16x32_f16(af, bfc[fc], acc[fc], 0, 0, 0);
#pragma unroll
        for (int fc = 0; fc < 8; ++fc) bfc[fc] = bfn[fc];
    }
#undef LOADA
#undef WRITEA

    const int mrow = w * 16 + (lane >> 4) * 4;
#pragma unroll
    for (int fc = 0; fc < 8; ++fc) {
        const int n = n0 + fc * 16 + rowb;
        const float bon = bo[n];
        const f32x4 c = acc[fc];
#pragma unroll
        for (int j = 0; j < 4; ++j) {
            const int m = mrow + j;
            if (row0 + m < MQ)
                out[(size_t)(row0 + m) * 256 + n] = c[j] + bon;
        }
    }
}

// ---------------------------------------------------------------------------
extern "C" void kernel_launch(void* const* d_in, const int* in_sizes, int n_in,
                              void* d_out, int out_size, void* d_ws, size_t ws_size,
                              hipStream_t stream)
{
    const float* query = (const float*)d_in[0];
    const float* refp  = (const float*)d_in[1];
    const float* value = (const float*)d_in[2];
    const float* Wv = (const float*)d_in[4];
    const float* bv = (const float*)d_in[5];
    const float* Ws = (const float*)d_in[6];
    const float* bs = (const float*)d_in[7];
    const float* Wa = (const float*)d_in[8];
    const float* ba = (const float*)d_in[9];
    const float* Wo = (const float*)d_in[10];
    const float* bo = (const float*)d_in[11];
    float* out = (float*)d_out;

    char* ws = (char*)d_ws;
    _Float16* vt_h  = (_Float16*)(ws + 0);          // 43520*256*2   = 22,282,240 B
    _Float16* tmp_h = (_Float16*)(ws + 22282240);   // 20000*256*2   = 10,240,000 B
    _Float16* Wvt   = (_Float16*)(ws + 32522240);   //                   131,072 B
    _Float16* Wsat  = (_Float16*)(ws + 32653312);   //                   196,608 B
    _Float16* Wot   = (_Float16*)(ws + 32849920);   //                   131,072 B
    float*    sxg   = (float*)   (ws + 32980992);   // 20000*128*4   = 10,240,000 B
    float*    syg   = (float*)   (ws + 43220992);
    float*    swg   = (float*)   (ws + 53460992);   // ends 63,700,992

    hipLaunchKernelGGL(k_prepw, dim3(896), dim3(256), 0, stream,
                       Wv, Ws, Wa, Wo, Wvt, Wsat, Wot);
    hipLaunchKernelGGL(k_front, dim3(NVB + NCB), dim3(256), 0, stream,
                       value, query, Wvt, Wsat, refp, bv, bs, ba,
                       vt_h, sxg, syg, swg);
    hipLaunchKernelGGL(k_gather, dim3(NB_B * NB_Q / 16 * NB_NH), dim3(256), 0, stream,
                       vt_h, sxg, syg, swg, tmp_h);
    hipLaunchKernelGGL(k_oproj_mm, dim3(MQB * 2), dim3(256), 0, stream,
                       tmp_h, Wot, bo, out);
}

// Round 12
// 99.393 us; speedup vs baseline: 1.5917x; 1.5917x over previous
//
#include <hip/hip_runtime.h>

#define NB_B  2
#define NB_Q  10000
#define NB_D  256
#define NB_NH 8
#define NB_NL 4
#define NB_NP 4
#define NB_HD 32
#define NB_S  21760   // 128*128 + 64*64 + 32*32 + 16*16
#define MQ    20000   // B*Q
#define MQB   313     // ceil(20000/64)
#define NVB   1360    // (B*S/64)*2  vproj blocks
#define NCB   939     // MQB*3       coords blocks

#define ASTR  536     // A oct stride in halfs: 268 words = 12 mod 32 (conflict-phase fix)
#define BSTR  1048    // B oct stride in halfs: 524 words = 12 mod 32

typedef _Float16 half8 __attribute__((ext_vector_type(8)));
typedef float f32x4 __attribute__((ext_vector_type(4)));

// ---------------------------------------------------------------------------
// Prep: transpose + fp16-convert weights to Wt[n][k] (k-major, 256 k each).
// ---------------------------------------------------------------------------
__global__ __launch_bounds__(256) void k_prepw(const float* __restrict__ Wv,
                                               const float* __restrict__ Ws,
                                               const float* __restrict__ Wa,
                                               const float* __restrict__ Wo,
                                               _Float16* __restrict__ Wvt,
                                               _Float16* __restrict__ Wsat,
                                               _Float16* __restrict__ Wot)
{
    const int k = threadIdx.x;
    const int nc = blockIdx.x;
    if (nc < 256) {
        Wvt[nc * 256 + k] = (_Float16)Wv[k * 256 + nc];
    } else if (nc < 640) {
        const int n = nc - 256;
        const float v = (n < 256) ? Ws[k * 256 + n] : Wa[k * 128 + (n - 256)];
        Wsat[n * 256 + k] = (_Float16)v;
    } else {
        const int n = nc - 640;
        Wot[n * 256 + k] = (_Float16)Wo[k * 256 + n];
    }
}

// ---------------------------------------------------------------------------
// k_front: co-launched vproj [0,NVB) + coords [NVB,NVB+NCB).
// BM=64, BN=128, BK=32, 2-buf LDS, reg prefetch-1, COALESCED staging:
//   A: thread -> row t>>3, float4-col t&7  (wave = 8 rows x 128B)
//   B: thread -> n   t>>2, oct       t&3  (wave = 16 n x 64B)
// LDS [oct][row][8] with oct stride = 12 mod 32 words: conflict-phase-clean.
// ---------------------------------------------------------------------------
__global__ __launch_bounds__(256) void k_front(const float* __restrict__ value,
                                               const float* __restrict__ query,
                                               const _Float16* __restrict__ Wvt,
                                               const _Float16* __restrict__ Wsat,
                                               const float* __restrict__ refp,
                                               const float* __restrict__ bv,
                                               const float* __restrict__ bs,
                                               const float* __restrict__ ba,
                                               _Float16* __restrict__ vt,
                                               float* __restrict__ sx,
                                               float* __restrict__ sy,
                                               float* __restrict__ sw)
{
    __shared__ __align__(16) _Float16 Ah[2][4 * ASTR];
    __shared__ __align__(16) _Float16 Bh[2][4 * BSTR];
    __shared__ float rp[64][8];            // 2 KB (coords only)

    const int t = threadIdx.x;
    const int lane = t & 63, w = t >> 6;
    const int bid = blockIdx.x;
    const bool isv = (bid < NVB);

    int row0, n0;
    const float* Asrc;
    const _Float16* Bsrc;
    if (isv) {
        n0 = (bid & 1) * 128;
        row0 = (bid >> 1) * 64;
        Asrc = value;
        Bsrc = Wvt;
    } else {
        const int cid = bid - NVB;
        n0 = (cid % 3) * 128;
        row0 = (cid / 3) * 64;
        Asrc = query;
        Bsrc = Wsat;
        const int i0 = row0 * 8 + t;
        rp[t >> 3][t & 7] = refp[min(i0, MQ * 8 - 1)];
        const int i1 = i0 + 256;
        rp[32 + (t >> 3)][t & 7] = refp[min(i1, MQ * 8 - 1)];
    }

    // coalesced staging maps
    const int arr = t >> 3;   // A row within 32-row half (i adds 32)
    const int acl = t & 7;    // A float4 col within 32-k tile
    const int bnn = t >> 2;   // B n within 64-row half (i adds 64)
    const int bcl = t & 3;    // B oct col

    const float* gA0;
    const float* gA1;
    {
        int r0i = row0 + arr, r1i = row0 + 32 + arr;
        if (!isv) { r0i = min(r0i, MQ - 1); r1i = min(r1i, MQ - 1); }
        gA0 = Asrc + (size_t)r0i * 256 + acl * 4;
        gA1 = Asrc + (size_t)r1i * 256 + acl * 4;
    }
    const _Float16* gB0 = Bsrc + (size_t)(n0 + bnn) * 256 + bcl * 8;
    const _Float16* gB1 = Bsrc + (size_t)(n0 + 64 + bnn) * 256 + bcl * 8;

    float4 ar0, ar1;
    uint4  br0, br1;
#define LOADT(kt) { ar0 = *reinterpret_cast<const float4*>(gA0 + (kt) * 32); \
                    ar1 = *reinterpret_cast<const float4*>(gA1 + (kt) * 32); \
                    br0 = *reinterpret_cast<const uint4*>(gB0 + (kt) * 32);  \
                    br1 = *reinterpret_cast<const uint4*>(gB1 + (kt) * 32); }

    LOADT(0);

    f32x4 acc[4][2];
#pragma unroll
    for (int fr = 0; fr < 4; ++fr)
#pragma unroll
        for (int fc = 0; fc < 2; ++fc) acc[fr][fc] = (f32x4){0.f, 0.f, 0.f, 0.f};

    const int rowb = lane & 15;
    const int kq = lane >> 4;
    const int awoff = (acl >> 1) * ASTR + arr * 8 + (acl & 1) * 4;
    int buf = 0;
#pragma unroll
    for (int kt = 0; kt < 8; ++kt) {
        {
            union { _Float16 h[4]; uint2 u; } p0, p1;
            p0.h[0] = (_Float16)ar0.x; p0.h[1] = (_Float16)ar0.y;
            p0.h[2] = (_Float16)ar0.z; p0.h[3] = (_Float16)ar0.w;
            p1.h[0] = (_Float16)ar1.x; p1.h[1] = (_Float16)ar1.y;
            p1.h[2] = (_Float16)ar1.z; p1.h[3] = (_Float16)ar1.w;
            *reinterpret_cast<uint2*>(&Ah[buf][awoff])           = p0.u;
            *reinterpret_cast<uint2*>(&Ah[buf][awoff + 32 * 8])  = p1.u;  // +32 rows
            *reinterpret_cast<uint4*>(&Bh[buf][bcl * BSTR + bnn * 8])        = br0;
            *reinterpret_cast<uint4*>(&Bh[buf][bcl * BSTR + (64 + bnn) * 8]) = br1;
        }
        if (kt < 7) LOADT(kt + 1);
        __syncthreads();

        half8 af[4], bf[2];
#pragma unroll
        for (int fr = 0; fr < 4; ++fr)
            af[fr] = *reinterpret_cast<const half8*>(&Ah[buf][kq * ASTR + (fr * 16 + rowb) * 8]);
#pragma unroll
        for (int fc = 0; fc < 2; ++fc)
            bf[fc] = *reinterpret_cast<const half8*>(&Bh[buf][kq * BSTR + (w * 32 + fc * 16 + rowb) * 8]);
#pragma unroll
        for (int fr = 0; fr < 4; ++fr)
#pragma unroll
            for (int fc = 0; fc < 2; ++fc)
                acc[fr][fc] = __builtin_amdgcn_mfma_f32_16x16x32_f16(af[fr], bf[fc], acc[fr][fc], 0, 0, 0);
        buf ^= 1;
    }
#undef LOADT

    // ---- epilogues ----
    if (isv) {
        const int b = (row0 >= NB_S) ? 1 : 0;
        const int sb = row0 - b * NB_S;
#pragma unroll
        for (int fc = 0; fc < 2; ++fc) {
            const int n = n0 + w * 32 + fc * 16 + rowb;
            const int h = n >> 5, hd = n & 31;
            const float bvn = bv[n];
#pragma unroll
            for (int fr = 0; fr < 4; ++fr) {
                const f32x4 c = acc[fr][fc];
#pragma unroll
                for (int j = 0; j < 4; ++j) {
                    const int m = fr * 16 + (lane >> 4) * 4 + j;
                    vt[((size_t)((b * NB_NH + h) * NB_S + (sb + m)) << 5) + hd] = (_Float16)(c[j] + bvn);
                }
            }
        }
    } else if (n0 < 256) {
#pragma unroll
        for (int fc = 0; fc < 2; ++fc) {
            const int n = n0 + w * 32 + fc * 16 + rowb;
            const int si = n >> 1, xy = n & 1;
            const int l = (n >> 3) & 3;
            const float dim = (float)(128 >> l);
            const float bsv = bs[n];
            float* dst = xy ? sy : sx;
#pragma unroll
            for (int fr = 0; fr < 4; ++fr) {
                const f32x4 c = acc[fr][fc];
#pragma unroll
                for (int j = 0; j < 4; ++j) {
                    const int m = fr * 16 + (lane >> 4) * 4 + j;
                    if (row0 + m < MQ) {
                        const float coord = rp[m][l * 2 + xy] * dim + (c[j] + bsv) - 0.5f;
                        dst[(size_t)(row0 + m) * 128 + si] = coord;
                    }
                }
            }
        }
    } else {
#pragma unroll
        for (int fc = 0; fc < 2; ++fc) {
            const int col = w * 32 + fc * 16 + rowb;
            const float bav = ba[col];
#pragma unroll
            for (int fr = 0; fr < 4; ++fr) {
                const f32x4 c = acc[fr][fc];
#pragma unroll
                for (int j = 0; j < 4; ++j) {
                    const int m = fr * 16 + (lane >> 4) * 4 + j;
                    float v = c[j] + bav;
                    float vm = v;
                    vm = fmaxf(vm, __shfl_xor(vm, 1));
                    vm = fmaxf(vm, __shfl_xor(vm, 2));
                    vm = fmaxf(vm, __shfl_xor(vm, 4));
                    vm = fmaxf(vm, __shfl_xor(vm, 8));
                    const float e = expf(v - vm);
                    float s = e;
                    s += __shfl_xor(s, 1);
                    s += __shfl_xor(s, 2);
                    s += __shfl_xor(s, 4);
                    s += __shfl_xor(s, 8);
                    if (row0 + m < MQ)
                        sw[(size_t)(row0 + m) * 128 + col] = e / s;
                }
            }
        }
    }
}

// ---------------------------------------------------------------------------
// gather: block = (16 queries, 1 head); head = blockIdx.x & 7 (XCD locality).
// ---------------------------------------------------------------------------
__global__ __launch_bounds__(256) void k_gather(const _Float16* __restrict__ vt,
                                                const float* __restrict__ sx,
                                                const float* __restrict__ sy,
                                                const float* __restrict__ sw,
                                                _Float16* __restrict__ tmp)
{
    __shared__ int   offs[16][16][4];
    __shared__ float wts[16][16][4];
    const int t = threadIdx.x;
    const int gid = blockIdx.x;
    const int h = gid & 7;
    const int row0 = (gid >> 3) * 16;
    const int b = (row0 >= NB_Q) ? 1 : 0;

    {
        const int r = t >> 4, s = t & 15;
        const size_t ci = (size_t)(row0 + r) * 128 + h * 16 + s;
        const float x = sx[ci], y = sy[ci], w = sw[ci];
        const int l = s >> 2;
        const int dim = 128 >> l;
        const int startL = (l == 0) ? 0 : (l == 1) ? 16384 : (l == 2) ? 20480 : 21504;
        const float x0f = floorf(x), y0f = floorf(y);
        const float lx = x - x0f, ly = y - y0f;
        const int ix = (int)x0f, iy = (int)y0f;
        const int ix0 = min(max(ix, 0), dim - 1), ix1 = min(max(ix + 1, 0), dim - 1);
        const int iy0 = min(max(iy, 0), dim - 1), iy1 = min(max(iy + 1, 0), dim - 1);
        const float vx0 = (ix >= 0 && ix < dim) ? 1.f : 0.f;
        const float vx1 = (ix + 1 >= 0 && ix + 1 < dim) ? 1.f : 0.f;
        const float vy0 = (iy >= 0 && iy < dim) ? 1.f : 0.f;
        const float vy1 = (iy + 1 >= 0 && iy + 1 < dim) ? 1.f : 0.f;
        offs[r][s][0] = (startL + iy0 * dim + ix0) * (NB_HD * 2);
        offs[r][s][1] = (startL + iy0 * dim + ix1) * (NB_HD * 2);
        offs[r][s][2] = (startL + iy1 * dim + ix0) * (NB_HD * 2);
        offs[r][s][3] = (startL + iy1 * dim + ix1) * (NB_HD * 2);
        wts[r][s][0] = w * (1.f - lx) * (1.f - ly) * vx0 * vy0;
        wts[r][s][1] = w * lx * (1.f - ly) * vx1 * vy0;
        wts[r][s][2] = w * (1.f - lx) * ly * vx0 * vy1;
        wts[r][s][3] = w * lx * ly * vx1 * vy1;
    }
    __syncthreads();

    const int r = t >> 4, hd2 = t & 15;
    const char* slab = reinterpret_cast<const char*>(vt)
                     + (size_t)(b * NB_NH + h) * NB_S * (NB_HD * 2);
    const int byo = hd2 * 4;
    float ax = 0.f, ay = 0.f;
#pragma unroll
    for (int s = 0; s < 16; ++s) {
        const int4   o = *reinterpret_cast<const int4*>(&offs[r][s][0]);
        const float4 w = *reinterpret_cast<const float4*>(&wts[r][s][0]);
        union { unsigned u; _Float16 h[2]; } c0, c1, c2, c3;
        c0.u = *reinterpret_cast<const unsigned*>(slab + (o.x + byo));
        c1.u = *reinterpret_cast<const unsigned*>(slab + (o.y + byo));
        c2.u = *reinterpret_cast<const unsigned*>(slab + (o.z + byo));
        c3.u = *reinterpret_cast<const unsigned*>(slab + (o.w + byo));
        ax = fmaf(w.x, (float)c0.h[0], ax); ay = fmaf(w.x, (float)c0.h[1], ay);
        ax = fmaf(w.y, (float)c1.h[0], ax); ay = fmaf(w.y, (float)c1.h[1], ay);
        ax = fmaf(w.z, (float)c2.h[0], ax); ay = fmaf(w.z, (float)c2.h[1], ay);
        ax = fmaf(w.w, (float)c3.h[0], ax); ay = fmaf(w.w, (float)c3.h[1], ay);
    }
    union { unsigned u; _Float16 h[2]; } p;
    p.h[0] = (_Float16)ax; p.h[1] = (_Float16)ay;
    *reinterpret_cast<unsigned*>(tmp + (size_t)(row0 + r) * 256 + h * 32 + hd2 * 2) = p.u;
}

// ---------------------------------------------------------------------------
// oproj: out = tmp @ Wo + bo. BM=64, BN=128 (2-way), BK=32, 2-buf,
// coalesced reg staging (A fp16: thread -> row t>>2, oct t&3).
// ---------------------------------------------------------------------------
__global__ __launch_bounds__(256) void k_oproj_mm(const _Float16* __restrict__ tmp,
                                                  const _Float16* __restrict__ Wot,
                                                  const float* __restrict__ bo,
                                                  float* __restrict__ out)
{
    __shared__ __align__(16) _Float16 Ao[2][4 * ASTR];
    __shared__ __align__(16) _Float16 Bh[2][4 * BSTR];
    const int t = threadIdx.x;
    const int lane = t & 63, w = t >> 6;
    const int bid = blockIdx.x;
    const int n0 = (bid & 1) * 128;
    const int row0 = (bid >> 1) * 64;

    const int arr = t >> 2;   // A row 0..63
    const int acl = t & 3;    // A oct
    const int bnn = t >> 2;   // B n within 64-half
    const int bcl = t & 3;    // B oct

    const _Float16* gA0 = tmp + (size_t)min(row0 + arr, MQ - 1) * 256 + acl * 8;
    const _Float16* gB0 = Wot + (size_t)(n0 + bnn) * 256 + bcl * 8;
    const _Float16* gB1 = Wot + (size_t)(n0 + 64 + bnn) * 256 + bcl * 8;

    uint4 ar0, br0, br1;
#define LOADT(kt) { ar0 = *reinterpret_cast<const uint4*>(gA0 + (kt) * 32); \
                    br0 = *reinterpret_cast<const uint4*>(gB0 + (kt) * 32); \
                    br1 = *reinterpret_cast<const uint4*>(gB1 + (kt) * 32); }

    LOADT(0);

    f32x4 acc[4][2];
#pragma unroll
    for (int fr = 0; fr < 4; ++fr)
#pragma unroll
        for (int fc = 0; fc < 2; ++fc) acc[fr][fc] = (f32x4){0.f, 0.f, 0.f, 0.f};

    const int rowb = lane & 15;
    const int kq = lane >> 4;
    int buf = 0;
#pragma unroll
    for (int kt = 0; kt < 8; ++kt) {
        *reinterpret_cast<uint4*>(&Ao[buf][acl * ASTR + arr * 8])            = ar0;
        *reinterpret_cast<uint4*>(&Bh[buf][bcl * BSTR + bnn * 8])            = br0;
        *reinterpret_cast<uint4*>(&Bh[buf][bcl * BSTR + (64 + bnn) * 8])     = br1;
        if (kt < 7) LOADT(kt + 1);
        __syncthreads();

        half8 af[4], bf[2];
#pragma unroll
        for (int fr = 0; fr < 4; ++fr)
            af[fr] = *reinterpret_cast<const half8*>(&Ao[buf][kq * ASTR + (fr * 16 + rowb) * 8]);
#pragma unroll
        for (int fc = 0; fc < 2; ++fc)
            bf[fc] = *reinterpret_cast<const half8*>(&Bh[buf][kq * BSTR + (w * 32 + fc * 16 + rowb) * 8]);
#pragma unroll
        for (int fr = 0; fr < 4; ++fr)
#pragma unroll
            for (int fc = 0; fc < 2; ++fc)
                acc[fr][fc] = __builtin_amdgcn_mfma_f32_16x16x32_f16(af[fr], bf[fc], acc[fr][fc], 0, 0, 0);
        buf ^= 1;
    }
#undef LOADT

#pragma unroll
    for (int fc = 0; fc < 2; ++fc) {
        const int n = n0 + w * 32 + fc * 16 + rowb;
        const float bon = bo[n];
#pragma unroll
        for (int fr = 0; fr < 4; ++fr) {
            const f32x4 c = acc[fr][fc];
#pragma unroll
            for (int j = 0; j < 4; ++j) {
                const int m = fr * 16 + (lane >> 4) * 4 + j;
                if (row0 + m < MQ)
                    out[(size_t)(row0 + m) * 256 + n] = c[j] + bon;
            }
        }
    }
}

// ---------------------------------------------------------------------------
extern "C" void kernel_launch(void* const* d_in, const int* in_sizes, int n_in,
                              void* d_out, int out_size, void* d_ws, size_t ws_size,
                              hipStream_t stream)
{
    const float* query = (const float*)d_in[0];
    const float* refp  = (const float*)d_in[1];
    const float* value = (const float*)d_in[2];
    const float* Wv = (const float*)d_in[4];
    const float* bv = (const float*)d_in[5];
    const float* Ws = (const float*)d_in[6];
    const float* bs = (const float*)d_in[7];
    const float* Wa = (const float*)d_in[8];
    const float* ba = (const float*)d_in[9];
    const float* Wo = (const float*)d_in[10];
    const float* bo = (const float*)d_in[11];
    float* out = (float*)d_out;

    char* ws = (char*)d_ws;
    _Float16* vt_h  = (_Float16*)(ws + 0);          // 43520*256*2   = 22,282,240 B
    _Float16* tmp_h = (_Float16*)(ws + 22282240);   // 20000*256*2   = 10,240,000 B
    _Float16* Wvt   = (_Float16*)(ws + 32522240);   //                   131,072 B
    _Float16* Wsat  = (_Float16*)(ws + 32653312);   //                   196,608 B
    _Float16* Wot   = (_Float16*)(ws + 32849920);   //                   131,072 B
    float*    sxg   = (float*)   (ws + 32980992);   // 20000*128*4   = 10,240,000 B
    float*    syg   = (float*)   (ws + 43220992);
    float*    swg   = (float*)   (ws + 53460992);   // ends 63,700,992

    hipLaunchKernelGGL(k_prepw, dim3(896), dim3(256), 0, stream,
                       Wv, Ws, Wa, Wo, Wvt, Wsat, Wot);
    hipLaunchKernelGGL(k_front, dim3(NVB + NCB), dim3(256), 0, stream,
                       value, query, Wvt, Wsat, refp, bv, bs, ba,
                       vt_h, sxg, syg, swg);
    hipLaunchKernelGGL(k_gather, dim3(NB_B * NB_Q / 16 * NB_NH), dim3(256), 0, stream,
                       vt_h, sxg, syg, swg, tmp_h);
    hipLaunchKernelGGL(k_oproj_mm, dim3(MQB * 2), dim3(256), 0, stream,
                       tmp_h, Wot, bo, out);
}